// Round 1
// baseline (340.720 us; speedup 1.0000x reference)
//
#include <hip/hip_runtime.h>
#include <hip/hip_bf16.h>

// LFQ forward fused kernels for MI355X (gfx950).
// Outputs in d_out (float32): out[16384*512], indices[16384] (as float), aux_loss[1]
// ws layout: P[256][4096] partial avg_prob sums (4 MB), then 2 scalars {C_sum, E_sum}

#define NS    16384      // samples = 4*4096
#define DIMV  512
#define CD    12
#define CS    4096
#define NOUT  (NS*DIMV)  // 8388608
#define AUXO  (NOUT+NS)  // 8404992
#define INVT2 200.0f     // 2 * inv_temperature
#define NBLK  256        // K1 blocks; 64 samples each

// -------- K1: xp, indices, out-projection, factorized softmax entropy + avg_prob partials
__global__ __launch_bounds__(512, 2) void k_main(
    const float* __restrict__ x,
    const float* __restrict__ w_in,  const float* __restrict__ b_in,
    const float* __restrict__ w_out, const float* __restrict__ b_out,
    float* __restrict__ out, float* __restrict__ idx_out,
    float* __restrict__ P, float* __restrict__ Csum) {

  __shared__ float s_wi[6144];   // w_in swizzled: [d][e4][sub] float4s
  __shared__ float s_wt[6144];   // w_out^T swizzled same layout
  __shared__ float s_pp[4096];   // block partial avg_prob
  __shared__ float s_xp[8][4][12];
  __shared__ float s_phi[8][64];
  __shared__ float s_h[8];

  const int t = threadIdx.x;

  // stage weights, swizzled so lane(sub) b128 reads are conflict-free:
  // element (d, e) with e = sub*32 + e4*4 + kk stored at f = ((d*128 + e4*16 + sub)*4 + kk)
  for (int k = 0; k < 12; ++k) {
    int f  = t + k * 512;
    int kk = f & 3;
    int q  = f >> 2;
    int sub = q & 15, e4 = (q >> 4) & 7, d = q >> 7;
    int e  = sub * 32 + e4 * 4 + kk;
    s_wi[f] = w_in[d * 512 + e];
    s_wt[f] = w_out[e * 12 + d];   // transpose of w_out[512][12]
  }
  for (int k = 0; k < 8; ++k) s_pp[t + k * 512] = 0.f;
  __syncthreads();

  const int wave = t >> 6, lane = t & 63;
  const int g = lane >> 4, sub = lane & 15;

  float acc[64];
  #pragma unroll
  for (int j = 0; j < 64; ++j) acc[j] = 0.f;
  float hacc = 0.f;

  float bin[12];
  #pragma unroll
  for (int d = 0; d < 12; ++d) bin[d] = b_in[d];

  for (int bt = 0; bt < 2; ++bt) {
    const int i = blockIdx.x * 64 + wave * 8 + bt * 4 + g;

    // ---- load x slice: 32 elems per lane
    const float4* xr = (const float4*)(x + i * 512 + sub * 32);
    float4 xv[8];
    #pragma unroll
    for (int e4 = 0; e4 < 8; ++e4) xv[e4] = xr[e4];

    // ---- partial dots for 12 dims
    float p[12];
    #pragma unroll
    for (int d = 0; d < 12; ++d) p[d] = 0.f;
    #pragma unroll
    for (int e4 = 0; e4 < 8; ++e4) {
      #pragma unroll
      for (int d = 0; d < 12; ++d) {
        float4 w4 = ((const float4*)s_wi)[d * 128 + e4 * 16 + sub];
        p[d] += xv[e4].x * w4.x + xv[e4].y * w4.y + xv[e4].z * w4.z + xv[e4].w * w4.w;
      }
    }
    // ---- reduce across the 16 lanes of this sample
    #pragma unroll
    for (int d = 0; d < 12; ++d) {
      #pragma unroll
      for (int m = 1; m <= 8; m <<= 1) p[d] += __shfl_xor(p[d], m, 16);
      p[d] += bin[d];
    }

    // ---- index (bit 11-d set iff xp_d > 0)
    unsigned idx = 0u;
    #pragma unroll
    for (int d = 0; d < 12; ++d) idx |= (p[d] > 0.f ? 1u : 0u) << (11 - d);
    if (sub == 0) idx_out[i] = (float)idx;

    // ---- out row: out[e] = b_out[e] + sum_d sign(xp_d) * w_out[e][d]
    #pragma unroll
    for (int e4 = 0; e4 < 8; ++e4) {
      float4 o = ((const float4*)b_out)[sub * 8 + e4];
      #pragma unroll
      for (int d = 0; d < 12; ++d) {
        float4 w4 = ((const float4*)s_wt)[d * 128 + e4 * 16 + sub];
        float s = p[d] > 0.f ? 1.f : -1.f;
        o.x += s * w4.x; o.y += s * w4.y; o.z += s * w4.z; o.w += s * w4.w;
      }
      ((float4*)(out + i * 512 + sub * 32))[e4] = o;
    }

    // ---- share xp with whole wave for entropy phase
    if (sub == 0) {
      #pragma unroll
      for (int d = 0; d < 12; ++d) s_xp[wave][g][d] = p[d];
    }
    // (same-wave LDS write->read; lockstep, compiler inserts lgkmcnt wait)

    // ---- entropy: all 64 lanes process each of the 4 samples
    #pragma unroll 1
    for (int s = 0; s < 4; ++s) {
      float xq[12];
      #pragma unroll
      for (int d = 0; d < 12; ++d) xq[d] = s_xp[wave][s][d];

      float hi = 0.f, lo = 0.f, ah = 0.f, al = 0.f;
      #pragma unroll
      for (int d = 0; d < 6; ++d) {
        int bh = (lane >> (5 - d)) & 1;
        hi += bh ? xq[d]     : -xq[d];
        lo += bh ? xq[6 + d] : -xq[6 + d];
        ah += fabsf(xq[d]);
        al += fabsf(xq[6 + d]);
      }
      float lhi = INVT2 * (hi - ah);   // <= 0, max over lanes == 0
      float llo = INVT2 * (lo - al);
      float ehi = __expf(lhi);
      float elo = __expf(llo);
      float Shi = ehi, Slo = elo;
      #pragma unroll
      for (int m = 1; m <= 32; m <<= 1) {
        Shi += __shfl_xor(Shi, m);
        Slo += __shfl_xor(Slo, m);
      }
      float phi = ehi / Shi;
      float psi = elo / Slo;
      float lnShi = __logf(Shi), lnSlo = __logf(Slo);
      // factorized per-sample entropy: H = -(sum phi log phi + sum psi log psi)
      hacc += phi * (lhi - lnShi) + psi * (llo - lnSlo);

      // avg_prob: code c = j*64 + lane -> p = phi_j * psi_lane
      s_phi[wave][lane] = phi;
      #pragma unroll
      for (int jq = 0; jq < 16; ++jq) {
        float4 f = ((const float4*)s_phi[wave])[jq];
        acc[jq * 4 + 0] += f.x * psi;
        acc[jq * 4 + 1] += f.y * psi;
        acc[jq * 4 + 2] += f.z * psi;
        acc[jq * 4 + 3] += f.w * psi;
      }
    }
  }

  // ---- block-level reduce of avg_prob partials
  #pragma unroll
  for (int j = 0; j < 64; ++j) atomicAdd(&s_pp[j * 64 + lane], acc[j]);

  // ---- per-sample-entropy accumulator: wave reduce, then block reduce
  #pragma unroll
  for (int m = 1; m <= 32; m <<= 1) hacc += __shfl_xor(hacc, m);
  if (lane == 0) s_h[wave] = hacc;
  __syncthreads();
  if (t == 0) {
    float hs = 0.f;
    for (int w2 = 0; w2 < 8; ++w2) hs += s_h[w2];
    atomicAdd(Csum, hs);
  }
  // ---- write block partial
  float4* P4 = (float4*)(P + (size_t)blockIdx.x * 4096);
  P4[t]       = ((float4*)s_pp)[t];
  P4[t + 512] = ((float4*)s_pp)[t + 512];
}

// -------- K2: reduce partials -> avg_prob, accumulate codebook entropy (exact, clipped)
__global__ __launch_bounds__(256) void k_reduce(const float* __restrict__ P,
                                                float* __restrict__ Esum) {
  __shared__ float red[16][17];
  __shared__ float ered[16];
  const int t = threadIdx.x;
  const int cl = t & 15, rg = t >> 4;
  const int c = blockIdx.x * 16 + cl;
  float s = 0.f;
  #pragma unroll
  for (int k = 0; k < 16; ++k) s += P[(size_t)(rg + k * 16) * 4096 + c];
  red[rg][cl] = s;
  __syncthreads();
  if (t < 16) {
    float tot = 0.f;
    #pragma unroll
    for (int r = 0; r < 16; ++r) tot += red[r][t];
    float pb = tot * (1.f / (float)NS);
    ered[t] = pb * __logf(fmaxf(pb, 1e-5f));   // p * log(clip(p, eps))
  }
  __syncthreads();
  if (t == 0) {
    float e = 0.f;
    #pragma unroll
    for (int r = 0; r < 16; ++r) e += ered[r];
    atomicAdd(Esum, e);
  }
}

// -------- K3: combine into aux_loss
__global__ void k_final(const float* __restrict__ Csum, const float* __restrict__ Esum,
                        float* __restrict__ aux) {
  if (threadIdx.x == 0) {
    float per_sample_entropy = -Csum[0] * (1.f / (float)NS);
    float codebook_entropy   = -Esum[0];
    aux[0] = 0.1f * (per_sample_entropy - codebook_entropy);
  }
}

extern "C" void kernel_launch(void* const* d_in, const int* in_sizes, int n_in,
                              void* d_out, int out_size, void* d_ws, size_t ws_size,
                              hipStream_t stream) {
  const float* x     = (const float*)d_in[0];
  const float* w_in  = (const float*)d_in[1];
  const float* b_in  = (const float*)d_in[2];
  const float* w_out = (const float*)d_in[3];
  const float* b_out = (const float*)d_in[4];
  float* out = (float*)d_out;

  float* P    = (float*)d_ws;                                   // 256*4096 f32 = 4 MB
  float* scal = (float*)((char*)d_ws + (size_t)NBLK * 4096 * 4); // {C_sum, E_sum}

  hipMemsetAsync(scal, 0, 2 * sizeof(float), stream);
  k_main<<<NBLK, 512, 0, stream>>>(x, w_in, b_in, w_out, b_out,
                                   out, out + NOUT, P, scal);
  k_reduce<<<256, 256, 0, stream>>>(P, scal + 1);
  k_final<<<1, 64, 0, stream>>>(scal, scal + 1, out + AUXO);
}

// Round 2
// 119.988 us; speedup vs baseline: 2.8396x; 2.8396x over previous
//
#include <hip/hip_runtime.h>
#include <hip/hip_bf16.h>

// LFQ forward fused kernels for MI355X (gfx950).
// Outputs in d_out (float32): out[16384*512], indices[16384] (as float), aux_loss[1]
// ws layout: P[256][4096] partial avg_prob sums (4 MB), then 2 scalars {C_sum, E_sum}

#define NS    16384      // samples = 4*4096
#define NOUT  (NS*512)   // 8388608
#define AUXO  (NOUT+NS)  // 8404992
#define INVT2 200.0f     // 2 * inv_temperature
#define NBLK  256        // K1 blocks; 64 samples each

// -------- K1: xp, indices, out-projection, factorized softmax entropy + avg_prob partials
__global__ __launch_bounds__(512, 2) void k_main(
    const float* __restrict__ x,
    const float* __restrict__ w_in,  const float* __restrict__ b_in,
    const float* __restrict__ w_out, const float* __restrict__ b_out,
    float* __restrict__ out, float* __restrict__ idx_out,
    float* __restrict__ P, float* __restrict__ Csum) {

  __shared__ float s_wi[6144];      // w_in swizzled: [d][e4][sub] float4s
  __shared__ float s_wt[6144];      // w_out^T swizzled same layout
  __shared__ float s_phi[64][64];   // per-sample high-6-bit softmax probs
  __shared__ float s_psi[64][64];   // per-sample low-6-bit softmax probs
  __shared__ float s_xp[8][8][12];  // per-wave xp broadcast
  __shared__ float s_h[8];

  const int t = threadIdx.x;

  // stage weights, swizzled so lane(sub) b128 reads are conflict-free:
  // element (d, e) with e = sub*32 + e4*4 + kk stored at f = ((d*128 + e4*16 + sub)*4 + kk)
  for (int k = 0; k < 12; ++k) {
    int f  = t + k * 512;
    int kk = f & 3;
    int q  = f >> 2;
    int sub = q & 15, e4 = (q >> 4) & 7, d = q >> 7;
    int e  = sub * 32 + e4 * 4 + kk;
    s_wi[f] = w_in[d * 512 + e];
    s_wt[f] = w_out[e * 12 + d];   // transpose of w_out[512][12]
  }
  __syncthreads();

  const int wave = t >> 6, lane = t & 63;
  const int g = lane >> 4, sub = lane & 15;

  float bin[12];
  #pragma unroll
  for (int d = 0; d < 12; ++d) bin[d] = b_in[d];

  // ---- two samples per lane (amortize every weight read over both)
  const int i0 = blockIdx.x * 64 + wave * 8 + g;
  const int i1 = i0 + 4;

  const float4* xr0 = (const float4*)(x + (size_t)i0 * 512 + sub * 32);
  const float4* xr1 = (const float4*)(x + (size_t)i1 * 512 + sub * 32);
  float4 xv0[8], xv1[8];
  #pragma unroll
  for (int e4 = 0; e4 < 8; ++e4) { xv0[e4] = xr0[e4]; xv1[e4] = xr1[e4]; }

  // ---- partial dots for 12 dims, both samples per weight read
  float p0[12], p1[12];
  #pragma unroll
  for (int d = 0; d < 12; ++d) { p0[d] = 0.f; p1[d] = 0.f; }
  #pragma unroll
  for (int e4 = 0; e4 < 8; ++e4) {
    #pragma unroll
    for (int d = 0; d < 12; ++d) {
      float4 w4 = ((const float4*)s_wi)[d * 128 + e4 * 16 + sub];
      p0[d] += xv0[e4].x * w4.x + xv0[e4].y * w4.y + xv0[e4].z * w4.z + xv0[e4].w * w4.w;
      p1[d] += xv1[e4].x * w4.x + xv1[e4].y * w4.y + xv1[e4].z * w4.z + xv1[e4].w * w4.w;
    }
  }
  // ---- reduce across the 16 lanes of each sample
  #pragma unroll
  for (int d = 0; d < 12; ++d) {
    #pragma unroll
    for (int m = 1; m <= 8; m <<= 1) {
      p0[d] += __shfl_xor(p0[d], m, 16);
      p1[d] += __shfl_xor(p1[d], m, 16);
    }
    p0[d] += bin[d];
    p1[d] += bin[d];
  }

  // ---- indices (bit 11-d set iff xp_d > 0)
  unsigned idx0 = 0u, idx1 = 0u;
  #pragma unroll
  for (int d = 0; d < 12; ++d) {
    idx0 |= (p0[d] > 0.f ? 1u : 0u) << (11 - d);
    idx1 |= (p1[d] > 0.f ? 1u : 0u) << (11 - d);
  }
  if (sub == 0) {
    idx_out[i0] = (float)idx0;
    idx_out[i1] = (float)idx1;
    #pragma unroll
    for (int d = 0; d < 12; ++d) {
      s_xp[wave][g][d]     = p0[d];
      s_xp[wave][4 + g][d] = p1[d];
    }
  }

  // ---- out rows: out[e] = b_out[e] + sum_d sign(xp_d) * w_out[e][d]
  float sg0[12], sg1[12];
  #pragma unroll
  for (int d = 0; d < 12; ++d) {
    sg0[d] = p0[d] > 0.f ? 1.f : -1.f;
    sg1[d] = p1[d] > 0.f ? 1.f : -1.f;
  }
  #pragma unroll
  for (int e4 = 0; e4 < 8; ++e4) {
    float4 bo = ((const float4*)b_out)[sub * 8 + e4];
    float4 o0 = bo, o1 = bo;
    #pragma unroll
    for (int d = 0; d < 12; ++d) {
      float4 w4 = ((const float4*)s_wt)[d * 128 + e4 * 16 + sub];
      o0.x += sg0[d] * w4.x; o0.y += sg0[d] * w4.y; o0.z += sg0[d] * w4.z; o0.w += sg0[d] * w4.w;
      o1.x += sg1[d] * w4.x; o1.y += sg1[d] * w4.y; o1.z += sg1[d] * w4.z; o1.w += sg1[d] * w4.w;
    }
    ((float4*)(out + (size_t)i0 * 512 + sub * 32))[e4] = o0;
    ((float4*)(out + (size_t)i1 * 512 + sub * 32))[e4] = o1;
  }

  // ---- entropy: all 64 lanes process each of the wave's 8 samples
  float hacc = 0.f;
  #pragma unroll 1
  for (int s = 0; s < 8; ++s) {
    float xq[12];
    #pragma unroll
    for (int d = 0; d < 12; ++d) xq[d] = s_xp[wave][s][d];

    float hi = 0.f, lo = 0.f, ah = 0.f, al = 0.f;
    #pragma unroll
    for (int d = 0; d < 6; ++d) {
      int bh = (lane >> (5 - d)) & 1;
      hi += bh ? xq[d]     : -xq[d];
      lo += bh ? xq[6 + d] : -xq[6 + d];
      ah += fabsf(xq[d]);
      al += fabsf(xq[6 + d]);
    }
    float lhi = INVT2 * (hi - ah);   // <= 0, max over lanes == 0
    float llo = INVT2 * (lo - al);
    float ehi = __expf(lhi);
    float elo = __expf(llo);
    float Shi = ehi, Slo = elo;
    #pragma unroll
    for (int m = 1; m <= 32; m <<= 1) {
      Shi += __shfl_xor(Shi, m);
      Slo += __shfl_xor(Slo, m);
    }
    float phi = ehi / Shi;
    float psi = elo / Slo;
    float lnShi = __logf(Shi), lnSlo = __logf(Slo);
    // factorized per-sample entropy: H = -(sum phi log phi + sum psi log psi)
    hacc += phi * (lhi - lnShi) + psi * (llo - lnSlo);

    const int ws = wave * 8 + s;
    s_phi[ws][lane] = phi;
    s_psi[ws][lane] = psi;
  }

  // ---- per-sample-entropy: wave reduce, then block reduce
  #pragma unroll
  for (int m = 1; m <= 32; m <<= 1) hacc += __shfl_xor(hacc, m);
  if (lane == 0) s_h[wave] = hacc;
  __syncthreads();   // also publishes s_phi/s_psi for phase B
  if (t == 0) {
    float hs = 0.f;
    for (int w2 = 0; w2 < 8; ++w2) hs += s_h[w2];
    atomicAdd(Csum, hs);
  }

  // ---- phase B: avg_prob partial P[j][l] = sum_s phi[s][j]*psi[s][l]
  // each thread owns a 4(j) x 2(l) code tile -> 8 accumulator registers
  const int jb = (t >> 5) * 4;   // 16 j-tiles of 4
  const int lb = (t & 31) * 2;   // 32 l-tiles of 2
  float a00 = 0.f, a01 = 0.f, a10 = 0.f, a11 = 0.f;
  float a20 = 0.f, a21 = 0.f, a30 = 0.f, a31 = 0.f;
  #pragma unroll 4
  for (int s = 0; s < 64; ++s) {
    float4 ph = *(const float4*)&s_phi[s][jb];
    float2 ps = *(const float2*)&s_psi[s][lb];
    a00 += ph.x * ps.x; a01 += ph.x * ps.y;
    a10 += ph.y * ps.x; a11 += ph.y * ps.y;
    a20 += ph.z * ps.x; a21 += ph.z * ps.y;
    a30 += ph.w * ps.x; a31 += ph.w * ps.y;
  }
  float* Pr = P + (size_t)blockIdx.x * 4096;
  *(float2*)&Pr[(jb + 0) * 64 + lb] = make_float2(a00, a01);
  *(float2*)&Pr[(jb + 1) * 64 + lb] = make_float2(a10, a11);
  *(float2*)&Pr[(jb + 2) * 64 + lb] = make_float2(a20, a21);
  *(float2*)&Pr[(jb + 3) * 64 + lb] = make_float2(a30, a31);
}

// -------- K2: reduce partials -> avg_prob, accumulate codebook entropy (exact, clipped)
__global__ __launch_bounds__(256) void k_reduce(const float* __restrict__ P,
                                                float* __restrict__ Esum) {
  __shared__ float red[16][17];
  __shared__ float ered[16];
  const int t = threadIdx.x;
  const int cl = t & 15, rg = t >> 4;
  const int c = blockIdx.x * 16 + cl;
  float s = 0.f;
  #pragma unroll
  for (int k = 0; k < 16; ++k) s += P[(size_t)(rg + k * 16) * 4096 + c];
  red[rg][cl] = s;
  __syncthreads();
  if (t < 16) {
    float tot = 0.f;
    #pragma unroll
    for (int r = 0; r < 16; ++r) tot += red[r][t];
    float pb = tot * (1.f / (float)NS);
    ered[t] = pb * __logf(fmaxf(pb, 1e-5f));   // p * log(clip(p, eps))
  }
  __syncthreads();
  if (t == 0) {
    float e = 0.f;
    #pragma unroll
    for (int r = 0; r < 16; ++r) e += ered[r];
    atomicAdd(Esum, e);
  }
}

// -------- K3: combine into aux_loss
__global__ void k_final(const float* __restrict__ Csum, const float* __restrict__ Esum,
                        float* __restrict__ aux) {
  if (threadIdx.x == 0) {
    float per_sample_entropy = -Csum[0] * (1.f / (float)NS);
    float codebook_entropy   = -Esum[0];
    aux[0] = 0.1f * (per_sample_entropy - codebook_entropy);
  }
}

extern "C" void kernel_launch(void* const* d_in, const int* in_sizes, int n_in,
                              void* d_out, int out_size, void* d_ws, size_t ws_size,
                              hipStream_t stream) {
  const float* x     = (const float*)d_in[0];
  const float* w_in  = (const float*)d_in[1];
  const float* b_in  = (const float*)d_in[2];
  const float* w_out = (const float*)d_in[3];
  const float* b_out = (const float*)d_in[4];
  float* out = (float*)d_out;

  float* P    = (float*)d_ws;                                    // 256*4096 f32 = 4 MB
  float* scal = (float*)((char*)d_ws + (size_t)NBLK * 4096 * 4); // {C_sum, E_sum}

  hipMemsetAsync(scal, 0, 2 * sizeof(float), stream);
  k_main<<<NBLK, 512, 0, stream>>>(x, w_in, b_in, w_out, b_out,
                                   out, out + NOUT, P, scal);
  k_reduce<<<256, 256, 0, stream>>>(P, scal + 1);
  k_final<<<1, 64, 0, stream>>>(scal, scal + 1, out + AUXO);
}